// Round 17
// baseline (66.491 us; speedup 1.0000x reference)
//
#include <hip/hip_runtime.h>
#include <cstdint>

#define B_     4096
#define D_     256
#define KK_    6
#define T_     256
#define DEPTH_ 6
#define C_     8
#define F1     1536   // D*K
#define F2     3072   // 2*F1
#define NROW   1536   // T*DEPTH
#define NALL   1792   // 256 att cols + 1536 p cols
#define BK     64
#define NIT    (F1 / BK)    // 24
#define NFB    24     // F1/64 blocks for prep_att
#define NBLK   448    // (4096/128) * (1792/128)
// fused pre-kernel block ranges
#define PRE_PREP  96                    // 24 x 4 tile-transpose blocks
#define PRE_SEL   (PRE_PREP + 384)      // 1536 rows / 4 per block
#define PRE_F     (PRE_SEL + 1024)      // 4096 b / 4 per block

using bf16x8 = __attribute__((ext_vector_type(8))) __bf16;
using f32x4  = __attribute__((ext_vector_type(4))) float;

__device__ inline float waveSum(float v) {
#pragma unroll
  for (int m = 32; m; m >>= 1) v += __shfl_xor(v, m, 64);
  return v;
}
__device__ inline int waveSumI(int v) {
#pragma unroll
  for (int m = 32; m; m >>= 1) v += __shfl_xor(v, m, 64);
  return v;
}

__device__ __forceinline__ void gload_lds16(const void* g, void* l) {
  __builtin_amdgcn_global_load_lds(
      (const __attribute__((address_space(1))) unsigned int*)g,
      (__attribute__((address_space(3))) unsigned int*)l, 16, 0, 0);
}

// ---------------------------------------------------------------------------
// K0: fused pre-GEMM work, partitioned by block range:
//   [0,96):      tile-transpose att_W -> w_all rows 0..255 + pc partials
//   [96,480):    per-row sparsemax of sel_logits -> dense w_all rows 256..+w_c
//   [480,1504):  f = sigmoid((x-thr)*exp(log_beta)) -> f_hi, 4 b's per block
// ---------------------------------------------------------------------------
__global__ __launch_bounds__(256) void fused_pre_kernel(
    const float* __restrict__ att_W, const float* __restrict__ sel_logits,
    const float* __restrict__ x, const float* __restrict__ thr,
    const float* __restrict__ log_beta,
    __bf16* __restrict__ w_all, float* __restrict__ w_c,
    float* __restrict__ pc, __bf16* __restrict__ f_hi)
{
  const int bid = blockIdx.x;
  if (bid < PRE_PREP) {
    // ---- prep_att ----
    __shared__ float Wl[64][65], Wh[64][65];
    const int fblk = (bid % NFB) * 64;
    const int tblk = (bid / NFB) * 64;
    const int tt = threadIdx.x & 63;
    const int f4 = threadIdx.x >> 6;
#pragma unroll
    for (int r = 0; r < 16; ++r) {
      const int f = r * 4 + f4;
      Wl[f][tt] = att_W[(size_t)(fblk + f) * T_ + tblk + tt];
      Wh[f][tt] = att_W[(size_t)(fblk + f + F1) * T_ + tblk + tt];
    }
    __syncthreads();
    const int t  = threadIdx.x >> 2;
    const int fq = threadIdx.x & 3;
#pragma unroll
    for (int pass = 0; pass < 4; ++pass) {
      const int f0 = pass * 16 + fq * 4;
      alignas(8) __bf16 hv[4];
#pragma unroll
      for (int e = 0; e < 4; ++e)
        hv[e] = (__bf16)(Wl[f0 + e][t] - Wh[f0 + e][t]);
      *(uint2*)&w_all[(size_t)(tblk + t) * F1 + fblk + f0] = *(const uint2*)hv;
    }
    if (threadIdx.x < 64) {
      float s = 0.f;
#pragma unroll
      for (int f = 0; f < 64; ++f) s += Wh[f][threadIdx.x];
      pc[(size_t)(bid % NFB) * T_ + tblk + threadIdx.x] = s;
    }
  } else if (bid < PRE_SEL) {
    // ---- sel sparsemax (1 wave per row, all-register Michelot) ----
    const int row  = (bid - PRE_PREP) * 4 + (threadIdx.x >> 6);
    const int lane = threadIdx.x & 63;
    const float* src = sel_logits + (size_t)row * F2;
    float4 z[12];
#pragma unroll
    for (int q = 0; q < 12; ++q)
      z[q] = *(const float4*)(src + q * 256 + lane * 4);

    float tau = -1e30f, taun = 0.f;
    int cprev = F2 + 1;
    for (int it = 0; it < 64; ++it) {
      float s = 0.f; int c = 0;
#pragma unroll
      for (int q = 0; q < 12; ++q) {
        const float* zq = (const float*)&z[q];
#pragma unroll
        for (int r = 0; r < 4; ++r) {
          const float v = zq[r];
          if (v > tau) { s += v; c++; }
        }
      }
      s = waveSum(s); c = waveSumI(c);
      taun = (s - 1.0f) / (float)c;
      if (c == cprev) break;
      cprev = c; tau = taun;
    }
    tau = taun;

    float chi = 0.f;
    __bf16* wrow = w_all + (size_t)(T_ + row) * F1;
#pragma unroll
    for (int q = 0; q < 6; ++q) {
      const float* zlo = (const float*)&z[q];
      const float* zhi = (const float*)&z[q + 6];
      alignas(8) __bf16 wv[4];
#pragma unroll
      for (int r = 0; r < 4; ++r) {
        float lo = zlo[r] - tau; lo = lo > 0.f ? lo : 0.f;
        float hi = zhi[r] - tau; hi = hi > 0.f ? hi : 0.f;
        chi += hi;
        wv[r] = (__bf16)(lo - hi);
      }
      *(uint2*)&wrow[q * 256 + lane * 4] = *(const uint2*)wv;
    }
    const float csum = waveSum(chi);
    if (lane == 0) w_c[row] = csum;
  } else {
    // ---- f: 4 b's per block, thr/beta hoisted ----
    const int base_b = (bid - PRE_SEL) * 4;
    const int d = threadIdx.x;
    float beta[KK_], th[KK_];
#pragma unroll
    for (int k = 0; k < KK_; ++k) {
      beta[k] = __expf(log_beta[d * KK_ + k]);
      th[k]   = thr[d * KK_ + k];
    }
#pragma unroll
    for (int j = 0; j < 4; ++j) {
      const int b = base_b + j;
      const float xv = x[(size_t)b * D_ + d];
      alignas(4) __bf16 hv[6];
#pragma unroll
      for (int k = 0; k < KK_; ++k) {
        const float tt = (xv - th[k]) * beta[k];
        const float s = 1.0f / (1.0f + __expf(-tt));
        hv[k] = (__bf16)s;
      }
      const size_t base = (size_t)b * F1 + d * KK_;
      const unsigned* hp = (const unsigned*)hv;
      unsigned* dh = (unsigned*)&f_hi[base];
      dh[0] = hp[0]; dh[1] = hp[1]; dh[2] = hp[2];
    }
  }
}

__global__ __launch_bounds__(256) void catt_kernel(
    const float* __restrict__ pc, const float* __restrict__ att_b,
    float* __restrict__ catt)
{
  const int t = threadIdx.x;
  float s = att_b[t];
  for (int i = 0; i < NFB; ++i) s += pc[(size_t)i * T_ + t];
  catt[t] = s;
}

// ---------------------------------------------------------------------------
// K3: 128x128-tile MFMA GEMM, 8 waves (512 threads) each owning a 64x32
// quadrant.  64 KB ping-pong LDS + counted vmcnt(4) + dual barrier +
// T5 s_setprio(1) around the MFMA cluster (role-split arbitration).
// ---------------------------------------------------------------------------
__global__ __launch_bounds__(512) void gemm_mfma_kernel(
    const __bf16* __restrict__ f_hi, const __bf16* __restrict__ w_all,
    float* __restrict__ P)
{
  __shared__ __bf16 As[2][128 * 64];
  __shared__ __bf16 Bs[2][128 * 64];
  const int linear = blockIdx.x;
  const int xcd  = linear & 7;
  const int slot = linear >> 3;          // 0..55
  const int bm = (((xcd & 3) << 3) + (slot & 7)) * 128;   // bm-group 0..3
  const int bn = (((xcd >> 2) * 7) + (slot >> 3)) * 128;  // bn-group 0..1
  const int tid = threadIdx.x;
  const int wid = tid >> 6, lane = tid & 63;
  const int wr = wid >> 2, wc = wid & 3;   // 2 x 4 wave grid, 64x32 each

  const int srow = lane >> 3;                 // 0..7 row within 8-row chunk
  const int skb8 = ((lane & 7) ^ srow) << 3;  // inverse-swizzled src elem off

  const int l15   = lane & 15;
  const int mask  = (lane & 7) << 4;
  const int khalf = (lane >> 4) << 4;
  int offA[4][2], offB[2][2];
#pragma unroll
  for (int m = 0; m < 4; ++m) {
    const int row = wr * 64 + m * 16 + l15;
#pragma unroll
    for (int s = 0; s < 2; ++s)
      offA[m][s] = row * 128 + (((s << 6) | khalf) ^ mask);
  }
#pragma unroll
  for (int n = 0; n < 2; ++n) {
    const int col = wc * 32 + n * 16 + l15;
#pragma unroll
    for (int s = 0; s < 2; ++s)
      offB[n][s] = col * 128 + (((s << 6) | khalf) ^ mask);
  }

  f32x4 acc[4][2] = {};

  auto stage = [&](int it, int buf) {
    const int kl = it * BK;
#pragma unroll
    for (int j = 0; j < 2; ++j) {
      const int q = wid * 2 + j;   // 16 chunks of 8 rows
      gload_lds16(f_hi  + (size_t)(bm + q * 8 + srow) * F1 + kl + skb8, &As[buf][q * 512]);
      gload_lds16(w_all + (size_t)(bn + q * 8 + srow) * F1 + kl + skb8, &Bs[buf][q * 512]);
    }
  };

  stage(0, 0);
  stage(1, 1);
  for (int it = 0; it < NIT; ++it) {
    const int cur = it & 1;
    // counted wait: stage(it)'s 4 loads landed; stage(it+1)'s 4 stay in flight
    if (it + 1 < NIT) asm volatile("s_waitcnt vmcnt(4)" ::: "memory");
    else              asm volatile("s_waitcnt vmcnt(0)" ::: "memory");
    __builtin_amdgcn_sched_barrier(0);
    __builtin_amdgcn_s_barrier();          // all waves' stage(it) visible
    __builtin_amdgcn_sched_barrier(0);

    const char* pa = (const char*)As[cur];
    const char* pb = (const char*)Bs[cur];
    __builtin_amdgcn_s_setprio(1);         // T5: favor MFMA-phase waves
#pragma unroll
    for (int s = 0; s < 2; ++s) {
      bf16x8 av[4], bv[2];
#pragma unroll
      for (int m = 0; m < 4; ++m) av[m] = *(const bf16x8*)(pa + offA[m][s]);
#pragma unroll
      for (int n = 0; n < 2; ++n) bv[n] = *(const bf16x8*)(pb + offB[n][s]);
#pragma unroll
      for (int m = 0; m < 4; ++m)
#pragma unroll
        for (int n = 0; n < 2; ++n)
          acc[m][n] = __builtin_amdgcn_mfma_f32_16x16x32_bf16(av[m], bv[n], acc[m][n], 0, 0, 0);
    }
    __builtin_amdgcn_s_setprio(0);
    __builtin_amdgcn_sched_barrier(0);
    __builtin_amdgcn_s_barrier();          // all waves done reading buf cur
    __builtin_amdgcn_sched_barrier(0);
    if (it + 2 < NIT) stage(it + 2, cur);  // overwrite buf cur for it+2
  }

  const int r0 = (lane >> 4) << 2;
#pragma unroll
  for (int m = 0; m < 4; ++m)
#pragma unroll
    for (int n = 0; n < 2; ++n)
#pragma unroll
      for (int r = 0; r < 4; ++r)
        P[(size_t)(bm + wr * 64 + m * 16 + r0 + r) * NALL + (bn + wc * 32 + n * 16 + l15)] =
            acc[m][n][r];
}

// ---------------------------------------------------------------------------
// K4: fused epilogue — wave 0: sparsemax over att logits (P cols 0..255)
// into LDS; then all 4 waves: leaf products and output.
// ---------------------------------------------------------------------------
__global__ __launch_bounds__(256) void epilogue_kernel(
    const float* __restrict__ P, const float* __restrict__ catt,
    const float* __restrict__ w_c,
    const float* __restrict__ leaf, float* __restrict__ out)
{
  const int b = blockIdx.x;
  __shared__ float a_val_sh[T_];
  __shared__ unsigned short a_t_sh[T_];
  __shared__ int nact_sh;
  __shared__ float oacc[4][C_];
  const int tid = threadIdx.x;
  const int wid = tid >> 6, lane = tid & 63;

  if (wid == 0) {
    float z[4];
#pragma unroll
    for (int j = 0; j < 4; ++j) {
      const int t = lane + 64 * j;
      z[j] = P[(size_t)b * NALL + t] + catt[t];
    }
    float tau = -1e30f, taun = 0.f;
    int cprev = T_ + 1;
    for (int it = 0; it < 40; ++it) {
      float s = 0.f; int c = 0;
#pragma unroll
      for (int j = 0; j < 4; ++j) if (z[j] > tau) { s += z[j]; c++; }
      s = waveSum(s); c = waveSumI(c);
      taun = (s - 1.0f) / (float)c;
      if (c == cprev) break;
      cprev = c; tau = taun;
    }
    tau = taun;
    float av[4]; int nnz = 0;
#pragma unroll
    for (int j = 0; j < 4; ++j) {
      float a = z[j] - tau; av[j] = a > 0.f ? a : 0.f;
      if (av[j] > 0.f) nnz++;
    }
    int incl = nnz;
#pragma unroll
    for (int off = 1; off < 64; off <<= 1) {
      const int n = __shfl_up(incl, off, 64);
      if (lane >= off) incl += n;
    }
    int pos = incl - nnz;
#pragma unroll
    for (int j = 0; j < 4; ++j) {
      if (av[j] > 0.f) {
        a_val_sh[pos] = av[j];
        a_t_sh[pos] = (unsigned short)(lane + 64 * j);
        pos++;
      }
    }
    if (lane == 63) nact_sh = incl;
  }
  __syncthreads();

  const int nact = nact_sh;
  float o[C_];
#pragma unroll
  for (int c = 0; c < C_; ++c) o[c] = 0.f;

  for (int i = wid; i < nact; i += 4) {
    const int t = (int)a_t_sh[i];
    const float* pp = P + (size_t)b * NALL + T_ + t * DEPTH_;
    const float* wc = w_c + t * DEPTH_;
    float prob = a_val_sh[i];
#pragma unroll
    for (int d = 0; d < DEPTH_; ++d) {
      float pv = wc[d] + pp[d];
      pv = pv < 1e-6f ? 1e-6f : (pv > 1.0f - 1e-6f ? 1.0f - 1e-6f : pv);
      prob *= ((lane >> d) & 1) ? pv : (1.0f - pv);
    }
    const float* lf = leaf + ((size_t)t * 64 + lane) * C_;
#pragma unroll
    for (int c = 0; c < C_; ++c) o[c] += prob * lf[c];
  }
#pragma unroll
  for (int c = 0; c < C_; ++c) o[c] = waveSum(o[c]);
  if (lane == 0) {
#pragma unroll
    for (int c = 0; c < C_; ++c) oacc[wid][c] = o[c];
  }
  __syncthreads();
  if (tid < C_)
    out[(size_t)b * C_ + tid] = oacc[0][tid] + oacc[1][tid] + oacc[2][tid] + oacc[3][tid];
}

// ---------------------------------------------------------------------------
extern "C" void kernel_launch(void* const* d_in, const int* in_sizes, int n_in,
                              void* d_out, int out_size, void* d_ws, size_t ws_size,
                              hipStream_t stream)
{
  const float* x        = (const float*)d_in[0];
  const float* thr      = (const float*)d_in[1];
  const float* log_beta = (const float*)d_in[2];
  const float* sel      = (const float*)d_in[3];
  const float* leaf     = (const float*)d_in[4];
  const float* att_W    = (const float*)d_in[5];
  const float* att_b    = (const float*)d_in[6];
  float* out = (float*)d_out;

  char* ws = (char*)d_ws;
  size_t off = 0;
  auto alloc = [&](size_t bytes) {
    char* p = ws + off;
    off = (off + bytes + 255) & ~(size_t)255;
    return p;
  };
  __bf16* f_hi   = (__bf16*)alloc((size_t)B_ * F1 * 2);        // 12.6 MB
  __bf16* w_all  = (__bf16*)alloc((size_t)NALL * F1 * 2);      //  5.5 MB
  float*  catt   = (float*)alloc((size_t)T_ * 4);
  float*  pc     = (float*)alloc((size_t)NFB * T_ * 4);
  float*  w_c    = (float*)alloc((size_t)NROW * 4);
  float*  P      = (float*)alloc((size_t)B_ * NALL * 4);       // 29.4 MB
  (void)ws_size; (void)in_sizes; (void)n_in; (void)out_size;   // ~48 MB total

  hipLaunchKernelGGL(fused_pre_kernel, dim3(PRE_F),  dim3(256), 0, stream,
                     att_W, sel, x, thr, log_beta, w_all, w_c, pc, f_hi);
  hipLaunchKernelGGL(catt_kernel,      dim3(1),      dim3(256), 0, stream, pc, att_b, catt);
  hipLaunchKernelGGL(gemm_mfma_kernel, dim3(NBLK),   dim3(512), 0, stream, f_hi, w_all, P);
  hipLaunchKernelGGL(epilogue_kernel,  dim3(B_),     dim3(256), 0, stream, P, catt, w_c, leaf, out);
}

// Round 18
// 59.193 us; speedup vs baseline: 1.1233x; 1.1233x over previous
//
#include <hip/hip_runtime.h>
#include <cstdint>

#define B_     4096
#define D_     256
#define KK_    6
#define T_     256
#define DEPTH_ 6
#define C_     8
#define F1     1536   // D*K
#define F2     3072   // 2*F1
#define NROW   1536   // T*DEPTH
#define NALL   1792   // 256 att cols + 1536 p cols
#define BK     64
#define NIT    (F1 / BK)    // 24
#define NFB    24     // F1/64 blocks for prep_att
#define NBLK   448    // (4096/128) * (1792/128)
// fused pre-kernel block ranges
#define PRE_PREP  96                    // 24 x 4 tile-transpose blocks
#define PRE_SEL   (PRE_PREP + 384)      // 1536 rows / 4 per block
#define PRE_F     (PRE_SEL + 1024)      // 4096 b / 4 per block

using bf16x8 = __attribute__((ext_vector_type(8))) __bf16;
using f32x4  = __attribute__((ext_vector_type(4))) float;

__device__ inline float waveSum(float v) {
#pragma unroll
  for (int m = 32; m; m >>= 1) v += __shfl_xor(v, m, 64);
  return v;
}
__device__ inline int waveSumI(int v) {
#pragma unroll
  for (int m = 32; m; m >>= 1) v += __shfl_xor(v, m, 64);
  return v;
}

__device__ __forceinline__ void gload_lds16(const void* g, void* l) {
  __builtin_amdgcn_global_load_lds(
      (const __attribute__((address_space(1))) unsigned int*)g,
      (__attribute__((address_space(3))) unsigned int*)l, 16, 0, 0);
}

// ---------------------------------------------------------------------------
// K0: fused pre-GEMM work, partitioned by block range:
//   [0,96):      tile-transpose att_W -> w_all rows 0..255 + pc partials
//   [96,480):    per-row sparsemax of sel_logits -> dense w_all rows 256..+w_c
//   [480,1504):  f = sigmoid((x-thr)*exp(log_beta)) -> f_hi, 4 b's per block
// ---------------------------------------------------------------------------
__global__ __launch_bounds__(256) void fused_pre_kernel(
    const float* __restrict__ att_W, const float* __restrict__ sel_logits,
    const float* __restrict__ x, const float* __restrict__ thr,
    const float* __restrict__ log_beta,
    __bf16* __restrict__ w_all, float* __restrict__ w_c,
    float* __restrict__ pc, __bf16* __restrict__ f_hi)
{
  const int bid = blockIdx.x;
  if (bid < PRE_PREP) {
    // ---- prep_att ----
    __shared__ float Wl[64][65], Wh[64][65];
    const int fblk = (bid % NFB) * 64;
    const int tblk = (bid / NFB) * 64;
    const int tt = threadIdx.x & 63;
    const int f4 = threadIdx.x >> 6;
#pragma unroll
    for (int r = 0; r < 16; ++r) {
      const int f = r * 4 + f4;
      Wl[f][tt] = att_W[(size_t)(fblk + f) * T_ + tblk + tt];
      Wh[f][tt] = att_W[(size_t)(fblk + f + F1) * T_ + tblk + tt];
    }
    __syncthreads();
    const int t  = threadIdx.x >> 2;
    const int fq = threadIdx.x & 3;
#pragma unroll
    for (int pass = 0; pass < 4; ++pass) {
      const int f0 = pass * 16 + fq * 4;
      alignas(8) __bf16 hv[4];
#pragma unroll
      for (int e = 0; e < 4; ++e)
        hv[e] = (__bf16)(Wl[f0 + e][t] - Wh[f0 + e][t]);
      *(uint2*)&w_all[(size_t)(tblk + t) * F1 + fblk + f0] = *(const uint2*)hv;
    }
    if (threadIdx.x < 64) {
      float s = 0.f;
#pragma unroll
      for (int f = 0; f < 64; ++f) s += Wh[f][threadIdx.x];
      pc[(size_t)(bid % NFB) * T_ + tblk + threadIdx.x] = s;
    }
  } else if (bid < PRE_SEL) {
    // ---- sel sparsemax (1 wave per row, all-register Michelot, warm start) --
    const int row  = (bid - PRE_PREP) * 4 + (threadIdx.x >> 6);
    const int lane = threadIdx.x & 63;
    const float* src = sel_logits + (size_t)row * F2;
    float4 z[12];
    float s_all = 0.f;
#pragma unroll
    for (int q = 0; q < 12; ++q) {
      z[q] = *(const float4*)(src + q * 256 + lane * 4);
      s_all += z[q].x + z[q].y + z[q].z + z[q].w;
    }
    // warm start = result of the first Michelot iteration (tau=-inf)
    float tau = (waveSum(s_all) - 1.0f) / (float)F2;
    float taun = tau;
    int cprev = F2;
    for (int it = 0; it < 63; ++it) {
      float s = 0.f; int c = 0;
#pragma unroll
      for (int q = 0; q < 12; ++q) {
        const float* zq = (const float*)&z[q];
#pragma unroll
        for (int r = 0; r < 4; ++r) {
          const float v = zq[r];
          if (v > tau) { s += v; c++; }
        }
      }
      s = waveSum(s); c = waveSumI(c);
      taun = (s - 1.0f) / (float)c;
      if (c == cprev) break;
      cprev = c; tau = taun;
    }
    tau = taun;

    float chi = 0.f;
    __bf16* wrow = w_all + (size_t)(T_ + row) * F1;
#pragma unroll
    for (int q = 0; q < 6; ++q) {
      const float* zlo = (const float*)&z[q];
      const float* zhi = (const float*)&z[q + 6];
      alignas(8) __bf16 wv[4];
#pragma unroll
      for (int r = 0; r < 4; ++r) {
        float lo = zlo[r] - tau; lo = lo > 0.f ? lo : 0.f;
        float hi = zhi[r] - tau; hi = hi > 0.f ? hi : 0.f;
        chi += hi;
        wv[r] = (__bf16)(lo - hi);
      }
      *(uint2*)&wrow[q * 256 + lane * 4] = *(const uint2*)wv;
    }
    const float csum = waveSum(chi);
    if (lane == 0) w_c[row] = csum;
  } else {
    // ---- f: 4 b's per block, thr/beta hoisted ----
    const int base_b = (bid - PRE_SEL) * 4;
    const int d = threadIdx.x;
    float beta[KK_], th[KK_];
#pragma unroll
    for (int k = 0; k < KK_; ++k) {
      beta[k] = __expf(log_beta[d * KK_ + k]);
      th[k]   = thr[d * KK_ + k];
    }
#pragma unroll
    for (int j = 0; j < 4; ++j) {
      const int b = base_b + j;
      const float xv = x[(size_t)b * D_ + d];
      alignas(4) __bf16 hv[6];
#pragma unroll
      for (int k = 0; k < KK_; ++k) {
        const float tt = (xv - th[k]) * beta[k];
        const float s = 1.0f / (1.0f + __expf(-tt));
        hv[k] = (__bf16)s;
      }
      const size_t base = (size_t)b * F1 + d * KK_;
      const unsigned* hp = (const unsigned*)hv;
      unsigned* dh = (unsigned*)&f_hi[base];
      dh[0] = hp[0]; dh[1] = hp[1]; dh[2] = hp[2];
    }
  }
}

// ---------------------------------------------------------------------------
// K3: 128x128-tile MFMA GEMM, 8 waves (512 threads) each owning a 64x32
// quadrant.  64 KB ping-pong LDS + counted vmcnt(4) + dual barrier.
// ---------------------------------------------------------------------------
__global__ __launch_bounds__(512) void gemm_mfma_kernel(
    const __bf16* __restrict__ f_hi, const __bf16* __restrict__ w_all,
    float* __restrict__ P)
{
  __shared__ __bf16 As[2][128 * 64];
  __shared__ __bf16 Bs[2][128 * 64];
  const int linear = blockIdx.x;
  const int xcd  = linear & 7;
  const int slot = linear >> 3;          // 0..55
  const int bm = (((xcd & 3) << 3) + (slot & 7)) * 128;   // bm-group 0..3
  const int bn = (((xcd >> 2) * 7) + (slot >> 3)) * 128;  // bn-group 0..1
  const int tid = threadIdx.x;
  const int wid = tid >> 6, lane = tid & 63;
  const int wr = wid >> 2, wc = wid & 3;   // 2 x 4 wave grid, 64x32 each

  const int srow = lane >> 3;                 // 0..7 row within 8-row chunk
  const int skb8 = ((lane & 7) ^ srow) << 3;  // inverse-swizzled src elem off

  const int l15   = lane & 15;
  const int mask  = (lane & 7) << 4;
  const int khalf = (lane >> 4) << 4;
  int offA[4][2], offB[2][2];
#pragma unroll
  for (int m = 0; m < 4; ++m) {
    const int row = wr * 64 + m * 16 + l15;
#pragma unroll
    for (int s = 0; s < 2; ++s)
      offA[m][s] = row * 128 + (((s << 6) | khalf) ^ mask);
  }
#pragma unroll
  for (int n = 0; n < 2; ++n) {
    const int col = wc * 32 + n * 16 + l15;
#pragma unroll
    for (int s = 0; s < 2; ++s)
      offB[n][s] = col * 128 + (((s << 6) | khalf) ^ mask);
  }

  f32x4 acc[4][2] = {};

  auto stage = [&](int it, int buf) {
    const int kl = it * BK;
#pragma unroll
    for (int j = 0; j < 2; ++j) {
      const int q = wid * 2 + j;   // 16 chunks of 8 rows
      gload_lds16(f_hi  + (size_t)(bm + q * 8 + srow) * F1 + kl + skb8, &As[buf][q * 512]);
      gload_lds16(w_all + (size_t)(bn + q * 8 + srow) * F1 + kl + skb8, &Bs[buf][q * 512]);
    }
  };

  stage(0, 0);
  stage(1, 1);
  for (int it = 0; it < NIT; ++it) {
    const int cur = it & 1;
    if (it + 1 < NIT) asm volatile("s_waitcnt vmcnt(4)" ::: "memory");
    else              asm volatile("s_waitcnt vmcnt(0)" ::: "memory");
    __builtin_amdgcn_sched_barrier(0);
    __builtin_amdgcn_s_barrier();          // all waves' stage(it) visible
    __builtin_amdgcn_sched_barrier(0);

    const char* pa = (const char*)As[cur];
    const char* pb = (const char*)Bs[cur];
    __builtin_amdgcn_s_setprio(1);
#pragma unroll
    for (int s = 0; s < 2; ++s) {
      bf16x8 av[4], bv[2];
#pragma unroll
      for (int m = 0; m < 4; ++m) av[m] = *(const bf16x8*)(pa + offA[m][s]);
#pragma unroll
      for (int n = 0; n < 2; ++n) bv[n] = *(const bf16x8*)(pb + offB[n][s]);
#pragma unroll
      for (int m = 0; m < 4; ++m)
#pragma unroll
        for (int n = 0; n < 2; ++n)
          acc[m][n] = __builtin_amdgcn_mfma_f32_16x16x32_bf16(av[m], bv[n], acc[m][n], 0, 0, 0);
    }
    __builtin_amdgcn_s_setprio(0);
    __builtin_amdgcn_sched_barrier(0);
    __builtin_amdgcn_s_barrier();          // all waves done reading buf cur
    __builtin_amdgcn_sched_barrier(0);
    if (it + 2 < NIT) stage(it + 2, cur);  // overwrite buf cur for it+2
  }

  const int r0 = (lane >> 4) << 2;
#pragma unroll
  for (int m = 0; m < 4; ++m)
#pragma unroll
    for (int n = 0; n < 2; ++n)
#pragma unroll
      for (int r = 0; r < 4; ++r)
        P[(size_t)(bm + wr * 64 + m * 16 + r0 + r) * NALL + (bn + wc * 32 + n * 16 + l15)] =
            acc[m][n][r];
}

// ---------------------------------------------------------------------------
// K4: epilogue — 4 b's per block, ONE WAVE PER b (no block sync).
// Per wave: catt inline from pc partials, warm-start Michelot sparsemax,
// ballot-broadcast over active trees, leaf products, output.
// ---------------------------------------------------------------------------
__global__ __launch_bounds__(256) void epilogue_kernel(
    const float* __restrict__ P, const float* __restrict__ pc,
    const float* __restrict__ att_b, const float* __restrict__ w_c,
    const float* __restrict__ leaf, float* __restrict__ out)
{
  const int b = blockIdx.x * 4 + (threadIdx.x >> 6);
  const int lane = threadIdx.x & 63;

  // z = P + catt (catt computed inline, same summation order as before)
  float z[4];
  float s_all = 0.f;
#pragma unroll
  for (int j = 0; j < 4; ++j) {
    const int t = lane + 64 * j;
    float cv = att_b[t];
#pragma unroll
    for (int i = 0; i < NFB; ++i) cv += pc[(size_t)i * T_ + t];
    z[j] = P[(size_t)b * NALL + t] + cv;
    s_all += z[j];
  }
  // warm-start Michelot over T=256
  float tau = (waveSum(s_all) - 1.0f) / (float)T_;
  float taun = tau;
  int cprev = T_;
  for (int it = 0; it < 39; ++it) {
    float s = 0.f; int c = 0;
#pragma unroll
    for (int j = 0; j < 4; ++j) if (z[j] > tau) { s += z[j]; c++; }
    s = waveSum(s); c = waveSumI(c);
    taun = (s - 1.0f) / (float)c;
    if (c == cprev) break;
    cprev = c; tau = taun;
  }
  tau = taun;
  float av[4];
#pragma unroll
  for (int j = 0; j < 4; ++j) {
    const float a = z[j] - tau;
    av[j] = a > 0.f ? a : 0.f;
  }

  // ballot-broadcast over active trees; lane = leaf index
  float o[C_];
#pragma unroll
  for (int c = 0; c < C_; ++c) o[c] = 0.f;
#pragma unroll
  for (int j = 0; j < 4; ++j) {
    unsigned long long msk = __ballot(av[j] > 0.f);
    while (msk) {
      const int src = (int)__ffsll((long long)msk) - 1;
      msk &= msk - 1;
      const float a = __shfl(av[j], src, 64);
      const int t = src + 64 * j;
      const float* pp = P + (size_t)b * NALL + T_ + t * DEPTH_;
      const float* wc = w_c + t * DEPTH_;
      float prob = a;
#pragma unroll
      for (int d = 0; d < DEPTH_; ++d) {
        float pv = wc[d] + pp[d];
        pv = pv < 1e-6f ? 1e-6f : (pv > 1.0f - 1e-6f ? 1.0f - 1e-6f : pv);
        prob *= ((lane >> d) & 1) ? pv : (1.0f - pv);
      }
      const float* lf = leaf + ((size_t)t * 64 + lane) * C_;
#pragma unroll
      for (int c = 0; c < C_; ++c) o[c] += prob * lf[c];
    }
  }
#pragma unroll
  for (int c = 0; c < C_; ++c) o[c] = waveSum(o[c]);
  if (lane == 0) {
#pragma unroll
    for (int c = 0; c < C_; ++c) out[(size_t)b * C_ + c] = o[c];
  }
}

// ---------------------------------------------------------------------------
extern "C" void kernel_launch(void* const* d_in, const int* in_sizes, int n_in,
                              void* d_out, int out_size, void* d_ws, size_t ws_size,
                              hipStream_t stream)
{
  const float* x        = (const float*)d_in[0];
  const float* thr      = (const float*)d_in[1];
  const float* log_beta = (const float*)d_in[2];
  const float* sel      = (const float*)d_in[3];
  const float* leaf     = (const float*)d_in[4];
  const float* att_W    = (const float*)d_in[5];
  const float* att_b    = (const float*)d_in[6];
  float* out = (float*)d_out;

  char* ws = (char*)d_ws;
  size_t off = 0;
  auto alloc = [&](size_t bytes) {
    char* p = ws + off;
    off = (off + bytes + 255) & ~(size_t)255;
    return p;
  };
  __bf16* f_hi   = (__bf16*)alloc((size_t)B_ * F1 * 2);        // 12.6 MB
  __bf16* w_all  = (__bf16*)alloc((size_t)NALL * F1 * 2);      //  5.5 MB
  float*  pc     = (float*)alloc((size_t)NFB * T_ * 4);
  float*  w_c    = (float*)alloc((size_t)NROW * 4);
  float*  P      = (float*)alloc((size_t)B_ * NALL * 4);       // 29.4 MB
  (void)ws_size; (void)in_sizes; (void)n_in; (void)out_size;   // ~48 MB total

  hipLaunchKernelGGL(fused_pre_kernel, dim3(PRE_F),  dim3(256), 0, stream,
                     att_W, sel, x, thr, log_beta, w_all, w_c, pc, f_hi);
  hipLaunchKernelGGL(gemm_mfma_kernel, dim3(NBLK),   dim3(512), 0, stream, f_hi, w_all, P);
  hipLaunchKernelGGL(epilogue_kernel,  dim3(B_ / 4), dim3(256), 0, stream,
                     P, pc, att_b, w_c, leaf, out);
}

// Round 19
// 57.825 us; speedup vs baseline: 1.1499x; 1.0237x over previous
//
#include <hip/hip_runtime.h>
#include <cstdint>

#define B_     4096
#define D_     256
#define KK_    6
#define T_     256
#define DEPTH_ 6
#define C_     8
#define F1     1536   // D*K
#define F2     3072   // 2*F1
#define NROW   1536   // T*DEPTH
#define NALL   1792   // 256 att cols + 1536 p cols
#define BK     64
#define NIT    (F1 / BK)    // 24
#define NFB    24     // F1/64 blocks for prep_att
#define NBLK   448    // (4096/128) * (1792/128)
// fused pre-kernel block ranges
#define PRE_PREP  96                    // 24 x 4 tile-transpose blocks
#define PRE_SEL   (PRE_PREP + 384)      // 1536 rows / 4 per block
#define PRE_F     (PRE_SEL + 1024)      // 4096 b / 4 per block

using bf16x8 = __attribute__((ext_vector_type(8))) __bf16;
using f32x4  = __attribute__((ext_vector_type(4))) float;

__device__ inline float waveSum(float v) {
#pragma unroll
  for (int m = 32; m; m >>= 1) v += __shfl_xor(v, m, 64);
  return v;
}
__device__ inline int waveSumI(int v) {
#pragma unroll
  for (int m = 32; m; m >>= 1) v += __shfl_xor(v, m, 64);
  return v;
}

__device__ __forceinline__ void gload_lds16(const void* g, void* l) {
  __builtin_amdgcn_global_load_lds(
      (const __attribute__((address_space(1))) unsigned int*)g,
      (__attribute__((address_space(3))) unsigned int*)l, 16, 0, 0);
}

// ---------------------------------------------------------------------------
// K0: fused pre-GEMM work, partitioned by block range:
//   [0,96):      tile-transpose att_W -> w_all rows 0..255 + pc partials
//   [96,480):    per-row sparsemax of sel_logits -> dense w_all rows 256..+w_c
//   [480,1504):  f = sigmoid((x-thr)*exp(log_beta)) -> f_hi, 4 b's per block
// ---------------------------------------------------------------------------
__global__ __launch_bounds__(256) void fused_pre_kernel(
    const float* __restrict__ att_W, const float* __restrict__ sel_logits,
    const float* __restrict__ x, const float* __restrict__ thr,
    const float* __restrict__ log_beta,
    __bf16* __restrict__ w_all, float* __restrict__ w_c,
    float* __restrict__ pc, __bf16* __restrict__ f_hi)
{
  const int bid = blockIdx.x;
  if (bid < PRE_PREP) {
    // ---- prep_att ----
    __shared__ float Wl[64][65], Wh[64][65];
    const int fblk = (bid % NFB) * 64;
    const int tblk = (bid / NFB) * 64;
    const int tt = threadIdx.x & 63;
    const int f4 = threadIdx.x >> 6;
#pragma unroll
    for (int r = 0; r < 16; ++r) {
      const int f = r * 4 + f4;
      Wl[f][tt] = att_W[(size_t)(fblk + f) * T_ + tblk + tt];
      Wh[f][tt] = att_W[(size_t)(fblk + f + F1) * T_ + tblk + tt];
    }
    __syncthreads();
    const int t  = threadIdx.x >> 2;
    const int fq = threadIdx.x & 3;
#pragma unroll
    for (int pass = 0; pass < 4; ++pass) {
      const int f0 = pass * 16 + fq * 4;
      alignas(8) __bf16 hv[4];
#pragma unroll
      for (int e = 0; e < 4; ++e)
        hv[e] = (__bf16)(Wl[f0 + e][t] - Wh[f0 + e][t]);
      *(uint2*)&w_all[(size_t)(tblk + t) * F1 + fblk + f0] = *(const uint2*)hv;
    }
    if (threadIdx.x < 64) {
      float s = 0.f;
#pragma unroll
      for (int f = 0; f < 64; ++f) s += Wh[f][threadIdx.x];
      pc[(size_t)(bid % NFB) * T_ + tblk + threadIdx.x] = s;
    }
  } else if (bid < PRE_SEL) {
    // ---- sel sparsemax (1 wave per row, all-register Michelot, warm start) --
    const int row  = (bid - PRE_PREP) * 4 + (threadIdx.x >> 6);
    const int lane = threadIdx.x & 63;
    const float* src = sel_logits + (size_t)row * F2;
    float4 z[12];
    float s_all = 0.f;
#pragma unroll
    for (int q = 0; q < 12; ++q) {
      z[q] = *(const float4*)(src + q * 256 + lane * 4);
      s_all += z[q].x + z[q].y + z[q].z + z[q].w;
    }
    float tau = (waveSum(s_all) - 1.0f) / (float)F2;
    float taun = tau;
    int cprev = F2;
    for (int it = 0; it < 63; ++it) {
      float s = 0.f; int c = 0;
#pragma unroll
      for (int q = 0; q < 12; ++q) {
        const float* zq = (const float*)&z[q];
#pragma unroll
        for (int r = 0; r < 4; ++r) {
          const float v = zq[r];
          if (v > tau) { s += v; c++; }
        }
      }
      s = waveSum(s); c = waveSumI(c);
      taun = (s - 1.0f) / (float)c;
      if (c == cprev) break;
      cprev = c; tau = taun;
    }
    tau = taun;

    float chi = 0.f;
    __bf16* wrow = w_all + (size_t)(T_ + row) * F1;
#pragma unroll
    for (int q = 0; q < 6; ++q) {
      const float* zlo = (const float*)&z[q];
      const float* zhi = (const float*)&z[q + 6];
      alignas(8) __bf16 wv[4];
#pragma unroll
      for (int r = 0; r < 4; ++r) {
        float lo = zlo[r] - tau; lo = lo > 0.f ? lo : 0.f;
        float hi = zhi[r] - tau; hi = hi > 0.f ? hi : 0.f;
        chi += hi;
        wv[r] = (__bf16)(lo - hi);
      }
      *(uint2*)&wrow[q * 256 + lane * 4] = *(const uint2*)wv;
    }
    const float csum = waveSum(chi);
    if (lane == 0) w_c[row] = csum;
  } else {
    // ---- f: 4 b's per block, thr/beta hoisted ----
    const int base_b = (bid - PRE_SEL) * 4;
    const int d = threadIdx.x;
    float beta[KK_], th[KK_];
#pragma unroll
    for (int k = 0; k < KK_; ++k) {
      beta[k] = __expf(log_beta[d * KK_ + k]);
      th[k]   = thr[d * KK_ + k];
    }
#pragma unroll
    for (int j = 0; j < 4; ++j) {
      const int b = base_b + j;
      const float xv = x[(size_t)b * D_ + d];
      alignas(4) __bf16 hv[6];
#pragma unroll
      for (int k = 0; k < KK_; ++k) {
        const float tt = (xv - th[k]) * beta[k];
        const float s = 1.0f / (1.0f + __expf(-tt));
        hv[k] = (__bf16)s;
      }
      const size_t base = (size_t)b * F1 + d * KK_;
      const unsigned* hp = (const unsigned*)hv;
      unsigned* dh = (unsigned*)&f_hi[base];
      dh[0] = hp[0]; dh[1] = hp[1]; dh[2] = hp[2];
    }
  }
}

// ---------------------------------------------------------------------------
// K3: 128x128-tile MFMA GEMM, 16 waves (1024 threads) each owning a 32x32
// quadrant (2x2 frags).  64 KB ping-pong LDS + counted vmcnt(2) + dual
// barrier.  2 blocks/CU x 16 waves = 8 waves/SIMD (max occupancy).
// ---------------------------------------------------------------------------
__global__ __launch_bounds__(1024) void gemm_mfma_kernel(
    const __bf16* __restrict__ f_hi, const __bf16* __restrict__ w_all,
    float* __restrict__ P)
{
  __shared__ __bf16 As[2][128 * 64];
  __shared__ __bf16 Bs[2][128 * 64];
  const int linear = blockIdx.x;
  const int xcd  = linear & 7;
  const int slot = linear >> 3;          // 0..55
  const int bm = (((xcd & 3) << 3) + (slot & 7)) * 128;   // bm-group 0..3
  const int bn = (((xcd >> 2) * 7) + (slot >> 3)) * 128;  // bn-group 0..1
  const int tid = threadIdx.x;
  const int wid = tid >> 6, lane = tid & 63;
  const int wr = wid >> 2, wc = wid & 3;   // 4 x 4 wave grid, 32x32 each

  const int srow = lane >> 3;                 // 0..7 row within 8-row chunk
  const int skb8 = ((lane & 7) ^ srow) << 3;  // inverse-swizzled src elem off

  const int l15   = lane & 15;
  const int mask  = (lane & 7) << 4;
  const int khalf = (lane >> 4) << 4;
  int offA[2][2], offB[2][2];
#pragma unroll
  for (int m = 0; m < 2; ++m) {
    const int row = wr * 32 + m * 16 + l15;
#pragma unroll
    for (int s = 0; s < 2; ++s)
      offA[m][s] = row * 128 + (((s << 6) | khalf) ^ mask);
  }
#pragma unroll
  for (int n = 0; n < 2; ++n) {
    const int col = wc * 32 + n * 16 + l15;
#pragma unroll
    for (int s = 0; s < 2; ++s)
      offB[n][s] = col * 128 + (((s << 6) | khalf) ^ mask);
  }

  f32x4 acc[2][2] = {};

  auto stage = [&](int it, int buf) {
    const int kl = it * BK;
    const int q = wid;   // 16 chunks of 8 rows, one per wave
    gload_lds16(f_hi  + (size_t)(bm + q * 8 + srow) * F1 + kl + skb8, &As[buf][q * 512]);
    gload_lds16(w_all + (size_t)(bn + q * 8 + srow) * F1 + kl + skb8, &Bs[buf][q * 512]);
  };

  stage(0, 0);
  stage(1, 1);
  for (int it = 0; it < NIT; ++it) {
    const int cur = it & 1;
    // counted wait: stage(it)'s 2 loads landed; stage(it+1)'s 2 stay in flight
    if (it + 1 < NIT) asm volatile("s_waitcnt vmcnt(2)" ::: "memory");
    else              asm volatile("s_waitcnt vmcnt(0)" ::: "memory");
    __builtin_amdgcn_sched_barrier(0);
    __builtin_amdgcn_s_barrier();          // all waves' stage(it) visible
    __builtin_amdgcn_sched_barrier(0);

    const char* pa = (const char*)As[cur];
    const char* pb = (const char*)Bs[cur];
    __builtin_amdgcn_s_setprio(1);
#pragma unroll
    for (int s = 0; s < 2; ++s) {
      bf16x8 av[2], bv[2];
#pragma unroll
      for (int m = 0; m < 2; ++m) av[m] = *(const bf16x8*)(pa + offA[m][s]);
#pragma unroll
      for (int n = 0; n < 2; ++n) bv[n] = *(const bf16x8*)(pb + offB[n][s]);
#pragma unroll
      for (int m = 0; m < 2; ++m)
#pragma unroll
        for (int n = 0; n < 2; ++n)
          acc[m][n] = __builtin_amdgcn_mfma_f32_16x16x32_bf16(av[m], bv[n], acc[m][n], 0, 0, 0);
    }
    __builtin_amdgcn_s_setprio(0);
    __builtin_amdgcn_sched_barrier(0);
    __builtin_amdgcn_s_barrier();          // all waves done reading buf cur
    __builtin_amdgcn_sched_barrier(0);
    if (it + 2 < NIT) stage(it + 2, cur);  // overwrite buf cur for it+2
  }

  const int r0 = (lane >> 4) << 2;
#pragma unroll
  for (int m = 0; m < 2; ++m)
#pragma unroll
    for (int n = 0; n < 2; ++n)
#pragma unroll
      for (int r = 0; r < 4; ++r)
        P[(size_t)(bm + wr * 32 + m * 16 + r0 + r) * NALL + (bn + wc * 32 + n * 16 + l15)] =
            acc[m][n][r];
}

// ---------------------------------------------------------------------------
// K4: epilogue — 4 b's per block, ONE WAVE PER b (no block sync).
// Per wave: catt inline from pc partials, warm-start Michelot sparsemax,
// ballot-broadcast over active trees, leaf products, output.
// ---------------------------------------------------------------------------
__global__ __launch_bounds__(256) void epilogue_kernel(
    const float* __restrict__ P, const float* __restrict__ pc,
    const float* __restrict__ att_b, const float* __restrict__ w_c,
    const float* __restrict__ leaf, float* __restrict__ out)
{
  const int b = blockIdx.x * 4 + (threadIdx.x >> 6);
  const int lane = threadIdx.x & 63;

  float z[4];
  float s_all = 0.f;
#pragma unroll
  for (int j = 0; j < 4; ++j) {
    const int t = lane + 64 * j;
    float cv = att_b[t];
#pragma unroll
    for (int i = 0; i < NFB; ++i) cv += pc[(size_t)i * T_ + t];
    z[j] = P[(size_t)b * NALL + t] + cv;
    s_all += z[j];
  }
  float tau = (waveSum(s_all) - 1.0f) / (float)T_;
  float taun = tau;
  int cprev = T_;
  for (int it = 0; it < 39; ++it) {
    float s = 0.f; int c = 0;
#pragma unroll
    for (int j = 0; j < 4; ++j) if (z[j] > tau) { s += z[j]; c++; }
    s = waveSum(s); c = waveSumI(c);
    taun = (s - 1.0f) / (float)c;
    if (c == cprev) break;
    cprev = c; tau = taun;
  }
  tau = taun;
  float av[4];
#pragma unroll
  for (int j = 0; j < 4; ++j) {
    const float a = z[j] - tau;
    av[j] = a > 0.f ? a : 0.f;
  }

  float o[C_];
#pragma unroll
  for (int c = 0; c < C_; ++c) o[c] = 0.f;
#pragma unroll
  for (int j = 0; j < 4; ++j) {
    unsigned long long msk = __ballot(av[j] > 0.f);
    while (msk) {
      const int src = (int)__ffsll((long long)msk) - 1;
      msk &= msk - 1;
      const float a = __shfl(av[j], src, 64);
      const int t = src + 64 * j;
      const float* pp = P + (size_t)b * NALL + T_ + t * DEPTH_;
      const float* wc = w_c + t * DEPTH_;
      float prob = a;
#pragma unroll
      for (int d = 0; d < DEPTH_; ++d) {
        float pv = wc[d] + pp[d];
        pv = pv < 1e-6f ? 1e-6f : (pv > 1.0f - 1e-6f ? 1.0f - 1e-6f : pv);
        prob *= ((lane >> d) & 1) ? pv : (1.0f - pv);
      }
      const float* lf = leaf + ((size_t)t * 64 + lane) * C_;
#pragma unroll
      for (int c = 0; c < C_; ++c) o[c] += prob * lf[c];
    }
  }
#pragma unroll
  for (int c = 0; c < C_; ++c) o[c] = waveSum(o[c]);
  if (lane == 0) {
#pragma unroll
    for (int c = 0; c < C_; ++c) out[(size_t)b * C_ + c] = o[c];
  }
}

// ---------------------------------------------------------------------------
extern "C" void kernel_launch(void* const* d_in, const int* in_sizes, int n_in,
                              void* d_out, int out_size, void* d_ws, size_t ws_size,
                              hipStream_t stream)
{
  const float* x        = (const float*)d_in[0];
  const float* thr      = (const float*)d_in[1];
  const float* log_beta = (const float*)d_in[2];
  const float* sel      = (const float*)d_in[3];
  const float* leaf     = (const float*)d_in[4];
  const float* att_W    = (const float*)d_in[5];
  const float* att_b    = (const float*)d_in[6];
  float* out = (float*)d_out;

  char* ws = (char*)d_ws;
  size_t off = 0;
  auto alloc = [&](size_t bytes) {
    char* p = ws + off;
    off = (off + bytes + 255) & ~(size_t)255;
    return p;
  };
  __bf16* f_hi   = (__bf16*)alloc((size_t)B_ * F1 * 2);        // 12.6 MB
  __bf16* w_all  = (__bf16*)alloc((size_t)NALL * F1 * 2);      //  5.5 MB
  float*  pc     = (float*)alloc((size_t)NFB * T_ * 4);
  float*  w_c    = (float*)alloc((size_t)NROW * 4);
  float*  P      = (float*)alloc((size_t)B_ * NALL * 4);       // 29.4 MB
  (void)ws_size; (void)in_sizes; (void)n_in; (void)out_size;   // ~48 MB total

  hipLaunchKernelGGL(fused_pre_kernel, dim3(PRE_F),  dim3(256),  0, stream,
                     att_W, sel, x, thr, log_beta, w_all, w_c, pc, f_hi);
  hipLaunchKernelGGL(gemm_mfma_kernel, dim3(NBLK),   dim3(1024), 0, stream, f_hi, w_all, P);
  hipLaunchKernelGGL(epilogue_kernel,  dim3(B_ / 4), dim3(256),  0, stream,
                     P, pc, att_b, w_c, leaf, out);
}